// Round 2
// baseline (480.014 us; speedup 1.0000x reference)
//
#include <hip/hip_runtime.h>

// BasicNCA: x:(16,1,512,512) f32, k:(1,1,3,3), w1:(10,1), b1:(10), w2:(1,10), steps=16
// out: (steps+1, 16, 1, 512, 512) f32 trajectory.
//
// Temporal blocking: fuse HALO=8 steps per kernel. Each block owns a 64x64 output
// tile; loads an 80x80 halo'd region into LDS once, iterates 8 steps in LDS
// (ping-pong, one __syncthreads per step), stores each step's central 64x64 to the
// trajectory directly from registers.
//
// Validity invariant: after step s, tile layer d (distance from tile edge) is valid
// iff d >= s; central 64x64 = layers >= 8 -> valid through all 8 steps.
// Out-of-image cells: reference SAME padding keeps them 0 EVERY step, so computed
// results are masked to exactly 0 when the global coord is outside the image
// (Round-1 bug: without the mask, border garbage propagated 1 px/step inward).
// Per-step math identical to the 451 us baseline kernel.

#define NCA_H 512
#define NCA_W 512
#define NCA_HW (NCA_H * NCA_W)
#define TX 80          // tile extent incl. halo
#define HALO 8         // steps fused per kernel launch
#define NG 20          // TX/4 column groups of 4 pixels
#define NACT 240       // NG * 12 row strips; threads 240..255 idle in compute

__global__ __launch_bounds__(256) void nca_fused(float* __restrict__ traj,   // slice 'base' of trajectory
                                                 size_t slice,               // elems per time slice (B*HW)
                                                 int nsteps,                 // steps this launch (<= HALO)
                                                 const float* __restrict__ kc,
                                                 const float* __restrict__ w1v,
                                                 const float* __restrict__ b1v,
                                                 const float* __restrict__ w2v) {
    __shared__ float buf[2][TX * TX];   // 2 x 25.6 KB ping-pong

    // weights: uniform loads
    float kk[9];
#pragma unroll
    for (int i = 0; i < 9; ++i) kk[i] = kc[i];
    float rw1[10], rb1[10], rw2[10];
#pragma unroll
    for (int o = 0; o < 10; ++o) { rw1[o] = w1v[o]; rb1[o] = b1v[o]; rw2[o] = w2v[o]; }

    const int bi = blockIdx.x;
    const int b  = bi >> 6;            // batch
    const int ty = (bi >> 3) & 7;      // tile row
    const int tx = bi & 7;             // tile col
    const int gh0 = ty * 64 - HALO;    // global coords of tile cell (0,0)
    const int gw0 = tx * 64 - HALO;

    // ---- stage 80x80 halo'd tile (zero-filled outside image) ----
    const float* sp = traj + (size_t)b * NCA_HW;
    for (int i = threadIdx.x; i < (TX * TX / 4); i += 256) {
        int row = i / NG;
        int c4  = i - row * NG;
        int gh  = gh0 + row;
        int gw  = gw0 + 4 * c4;        // multiple of 4 -> float4 wholly in or out
        float4 v = make_float4(0.f, 0.f, 0.f, 0.f);
        if (((unsigned)gh < NCA_H) && ((unsigned)gw < NCA_W))
            v = *(const float4*)(sp + (size_t)gh * NCA_W + gw);
        *(float4*)&buf[0][row * TX + 4 * c4] = v;
    }
    // rows 0 and 79 of buf[1] are never written by compute; zero them so stale
    // LDS bits (possibly NaN) can't enter the (invalid-but-computed) edge rows.
    if (threadIdx.x < 2 * NG) {
        int row = (threadIdx.x < NG) ? 0 : (TX - 1);
        int c4  = threadIdx.x % NG;
        *(float4*)&buf[1][row * TX + 4 * c4] = make_float4(0.f, 0.f, 0.f, 0.f);
    }
    __syncthreads();

    // ---- compute mapping: 20 col groups x 12 row strips (rows 1..78) ----
    const int tid = threadIdx.x;
    const bool active = tid < NACT;
    const int g  = tid % NG;
    const int rb = tid / NG;
    const int w0 = g * 4;
    const int r0 = (rb < 6) ? (1 + 7 * rb) : (43 + 6 * (rb - 6));
    const int r1 = r0 + ((rb < 6) ? 7 : 6);
    // store predicate: this group's 4 cols inside the central 64
    const bool colStore = active && (w0 >= HALO) && (w0 < TX - HALO);
    // image-membership of this thread's 4 columns (4-aligned -> wholly in/out)
    const bool colIn = ((unsigned)(gw0 + w0) < NCA_W);
    // clamped edge indices (corrupt only layer-0 cells, which are invalid anyway)
    const int wl = (w0 > 0) ? (w0 - 1) : 0;
    const int wr = (w0 + 4 < TX) ? (w0 + 4) : (TX - 1);

    int cur = 0;
    for (int s = 1; s <= nsteps; ++s) {
        const float* cb = buf[cur];
        float* nb = buf[cur ^ 1];
        float* gout = traj + (size_t)s * slice + (size_t)b * NCA_HW;
        if (active) {
            for (int r = r0; r < r1; ++r) {
                const bool ok = colIn && ((unsigned)(gh0 + r) < NCA_H);
                float rv[3][6];   // rows r-1..r+1, cols w0-1..w0+4
#pragma unroll
                for (int rr = 0; rr < 3; ++rr) {
                    const float* rp = cb + (r - 1 + rr) * TX;
                    float4 c4v = *(const float4*)(rp + w0);
                    rv[rr][0] = rp[wl];
                    rv[rr][1] = c4v.x; rv[rr][2] = c4v.y;
                    rv[rr][3] = c4v.z; rv[rr][4] = c4v.w;
                    rv[rr][5] = rp[wr];
                }
                float4 res;
                float* resp = (float*)&res;
#pragma unroll
                for (int j = 0; j < 4; ++j) {
                    float sacc = 0.f;
#pragma unroll
                    for (int rr = 0; rr < 3; ++rr) {
                        sacc = fmaf(kk[rr * 3 + 0], rv[rr][j],     sacc);
                        sacc = fmaf(kk[rr * 3 + 1], rv[rr][j + 1], sacc);
                        sacc = fmaf(kk[rr * 3 + 2], rv[rr][j + 2], sacc);
                    }
                    float d = sacc - 1.0f;
                    float gg = __expf(-d * d);
                    float acc = 0.f;
#pragma unroll
                    for (int o = 0; o < 10; ++o) {
                        float hm = fmaxf(fmaf(rw1[o], gg, rb1[o]), 0.f);
                        acc = fmaf(rw2[o], hm, acc);
                    }
                    float sig = __fdividef(1.0f, 1.0f + __expf(-acc));
                    float val = rv[1][j + 1] + (sig - 0.5f);   // x + (y - 0.5)
                    resp[j] = ok ? val : 0.f;                  // SAME-padding pin
                }
                *(float4*)&nb[r * TX + w0] = res;
                if (colStore && r >= HALO && r < TX - HALO)
                    *(float4*)(gout + (size_t)(gh0 + r) * NCA_W + (gw0 + w0)) = res;
            }
        }
        __syncthreads();
        cur ^= 1;
    }
}

extern "C" void kernel_launch(void* const* d_in, const int* in_sizes, int n_in,
                              void* d_out, int out_size, void* d_ws, size_t ws_size,
                              hipStream_t stream) {
    const float* x  = (const float*)d_in[0];
    const float* k  = (const float*)d_in[1];
    const float* w1 = (const float*)d_in[2];
    const float* b1 = (const float*)d_in[3];
    const float* w2 = (const float*)d_in[4];
    float* out = (float*)d_out;

    const size_t slice = (size_t)in_sizes[0];           // 16*512*512 = 4194304
    const int steps = out_size / (int)slice - 1;        // 16
    const int B = (int)(slice / NCA_HW);                // 16

    // slice 0 = initial state (kernel 1 stages from it, incl. neighbor-tile halos)
    hipMemcpyAsync(out, x, slice * sizeof(float), hipMemcpyDeviceToDevice, stream);

    const int blocks = B * 64;                          // 16 batches x 8x8 tiles
    for (int base = 0; base < steps; base += HALO) {
        int ns = steps - base;
        if (ns > HALO) ns = HALO;
        nca_fused<<<blocks, 256, 0, stream>>>(out + (size_t)base * slice, slice, ns,
                                              k, w1, b1, w2);
    }
}

// Round 4
// 453.608 us; speedup vs baseline: 1.0582x; 1.0582x over previous
//
#include <hip/hip_runtime.h>

// BasicNCA: x:(16,1,512,512) f32, k:(1,1,3,3), w1:(10,1), b1:(10), w2:(1,10), steps=16
// out: (steps+1, 16, 1, 512, 512) f32 trajectory.
//
// Temporal blocking, HALO=8 steps/kernel, 64x64 central tile, 80x80 LDS ping-pong.
// Rolling 4-row register window: each LDS row read ONCE (1 ds_read_b128), edge
// columns via __shfl_up/__shfl_down.
//
// Round-4 fix vs Round-3 (absmax 0.695): shfl seams are at WAVE boundaries and
// 64 % 20 != 0, so strips straddled waves and seam garbage landed in CENTRAL
// columns (e.g. col 15/16 at tid 63/64). Now strips are wave-aligned: 60 active
// lanes/wave = 3 strips x 20 groups; every intra-wave seam (lane 0, 19|20, 39|40,
// 59|60) feeds only W[0] of g=0 or W[5] of g=19 -> tile cols -1/80 -> outputs at
// layer-0 cols 0/79: invalid by the layer invariant, never stored, NaN-safe
// (garbage at layer d reaches stored cells only after step d+1 > 8).
//
// Validity invariant: after step s, tile layer d valid iff d >= s; central 64x64 =
// layers >= 8. Out-of-image results pinned to exact 0 (SAME padding).
// Per-step math order identical to the 451us baseline (absmax 0.015625).

#define NCA_H 512
#define NCA_W 512
#define NCA_HW (NCA_H * NCA_W)
#define TX 80          // tile extent incl. halo
#define HALO 8         // steps fused per kernel launch
#define NG 20          // TX/4 column groups

// load tile row 'rrow', cols w0-1..w0+4 into W[0..5] (edges via shfl)
#define LOADR(W, rrow) do {                                                  \
    const float4 q_ = *(const float4*)(cb + (rrow) * TX + w0);               \
    W[1] = q_.x; W[2] = q_.y; W[3] = q_.z; W[4] = q_.w;                      \
    W[0] = __shfl_up(q_.w, 1);                                               \
    W[5] = __shfl_down(q_.x, 1);                                             \
} while (0)

// compute tile row 'rrow' from window rows Wm (r-1), Wc (r), Wp (r+1)
#define COMPR(Wm, Wc, Wp, rrow) do {                                         \
    const int rr_ = (rrow);                                                  \
    const bool ok_ = colIn && ((unsigned)(gh0 + rr_) < NCA_H);               \
    float4 res_; float* rp_ = (float*)&res_;                                 \
    _Pragma("unroll")                                                        \
    for (int j = 0; j < 4; ++j) {                                            \
        float s_ = 0.f;                                                      \
        s_ = fmaf(kk[0], Wm[j],     s_);                                     \
        s_ = fmaf(kk[1], Wm[j + 1], s_);                                     \
        s_ = fmaf(kk[2], Wm[j + 2], s_);                                     \
        s_ = fmaf(kk[3], Wc[j],     s_);                                     \
        s_ = fmaf(kk[4], Wc[j + 1], s_);                                     \
        s_ = fmaf(kk[5], Wc[j + 2], s_);                                     \
        s_ = fmaf(kk[6], Wp[j],     s_);                                     \
        s_ = fmaf(kk[7], Wp[j + 1], s_);                                     \
        s_ = fmaf(kk[8], Wp[j + 2], s_);                                     \
        float d_ = s_ - 1.0f;                                                \
        float g_ = __expf(-d_ * d_);                                         \
        float a_ = 0.f;                                                      \
        _Pragma("unroll")                                                    \
        for (int o = 0; o < 10; ++o) {                                       \
            float h_ = fmaxf(fmaf(rw1[o], g_, rb1[o]), 0.f);                 \
            a_ = fmaf(rw2[o], h_, a_);                                       \
        }                                                                    \
        float sg_ = __fdividef(1.0f, 1.0f + __expf(-a_));                    \
        float v_ = Wc[j + 1] + (sg_ - 0.5f);                                 \
        rp_[j] = ok_ ? v_ : 0.f;                                             \
    }                                                                        \
    *(float4*)&nb[rr_ * TX + w0] = res_;                                     \
    if (colStore && rr_ >= HALO && rr_ < TX - HALO)                          \
        *(float4*)(gout + (size_t)(gh0 + rr_) * NCA_W + (gw0 + w0)) = res_;  \
} while (0)

__global__ __launch_bounds__(256, 3) void nca_fused(
        const float* __restrict__ src,   // state at step 'base' (x or traj slice)
        float* __restrict__ traj,        // points at slice 'base' of trajectory
        size_t slice, int nsteps, int writeInit,
        const float* __restrict__ kc, const float* __restrict__ w1v,
        const float* __restrict__ b1v, const float* __restrict__ w2v) {
    __shared__ float buf[2][TX * TX];   // 2 x 25.6 KB ping-pong

    float kk[9];
#pragma unroll
    for (int i = 0; i < 9; ++i) kk[i] = kc[i];
    float rw1[10], rb1[10], rw2[10];
#pragma unroll
    for (int o = 0; o < 10; ++o) { rw1[o] = w1v[o]; rb1[o] = b1v[o]; rw2[o] = w2v[o]; }

    const int bi = blockIdx.x;
    const int b  = bi >> 6;            // batch
    const int ty = (bi >> 3) & 7;      // tile row
    const int tx = bi & 7;             // tile col
    const int gh0 = ty * 64 - HALO;
    const int gw0 = tx * 64 - HALO;

    // ---- stage 80x80 halo'd tile from src; kernel 1 also emits slice 0 ----
    const float* sp = src + (size_t)b * NCA_HW;
    float* ip = traj + (size_t)b * NCA_HW;
    for (int i = threadIdx.x; i < (TX * TX / 4); i += 256) {
        int row = i / NG;
        int c4  = i - row * NG;
        int gh  = gh0 + row;
        int gw  = gw0 + 4 * c4;
        float4 v = make_float4(0.f, 0.f, 0.f, 0.f);
        if (((unsigned)gh < NCA_H) && ((unsigned)gw < NCA_W))
            v = *(const float4*)(sp + (size_t)gh * NCA_W + gw);
        *(float4*)&buf[0][4 * i] = v;   // row*TX + 4*c4 == 4*i (20*16B == TX row)
        if (writeInit && row >= HALO && row < TX - HALO &&
            c4 >= (HALO / 4) && c4 < (TX - HALO) / 4)
            *(float4*)(ip + (size_t)gh * NCA_W + gw) = v;
    }
    // rows 0/79 of buf[1] never written by compute; zero once (keep finite)
    if (threadIdx.x < 2 * NG) {
        int row = (threadIdx.x < NG) ? 0 : (TX - 1);
        int c4  = threadIdx.x % NG;
        *(float4*)&buf[1][row * TX + 4 * c4] = make_float4(0.f, 0.f, 0.f, 0.f);
    }
    __syncthreads();

    // ---- compute mapping: wave-aligned. 60 active lanes/wave = 3 strips x 20
    //      column groups; 4 waves -> 12 strips covering rows 1..78. ----
    const int tid  = threadIdx.x;
    const int lane = tid & 63;
    const int wid  = tid >> 6;
    const bool active = lane < 60;
    const int g    = lane % 20;              // column group within strip
    const int sidx = wid * 3 + lane / 20;    // strip index 0..11
    const int w0   = g * 4;
    const int r0   = (sidx < 6) ? (1 + 7 * sidx) : (43 + 6 * (sidx - 6));
    const bool n7  = (sidx < 6);             // 7-row strip?
    const bool colStore = active && (w0 >= HALO) && (w0 < TX - HALO);
    const bool colIn = ((unsigned)(gw0 + w0) < NCA_W);

    int cur = 0;
    for (int s = 1; s <= nsteps; ++s) {
        const float* cb = buf[cur];
        float* nb = buf[cur ^ 1];
        float* gout = traj + (size_t)s * slice + (size_t)b * NCA_HW;
        if (active) {
            float A[6], B[6], C[6], D[6];
            // prologue: fill window, then steady-state 1 load per compute,
            // each load issued one compute-phase ahead of its first use.
            LOADR(A, r0 - 1); LOADR(B, r0);
            LOADR(C, r0 + 1); LOADR(D, r0 + 2);
            COMPR(A, B, C, r0);       LOADR(A, r0 + 3);
            COMPR(B, C, D, r0 + 1);   LOADR(B, r0 + 4);
            COMPR(C, D, A, r0 + 2);   LOADR(C, r0 + 5);
            COMPR(D, A, B, r0 + 3);   LOADR(D, r0 + 6);
            COMPR(A, B, C, r0 + 4);
            COMPR(B, C, D, r0 + 5);
            if (n7) { LOADR(A, r0 + 7); COMPR(C, D, A, r0 + 6); }
        }
        __syncthreads();
        cur ^= 1;
    }
}

extern "C" void kernel_launch(void* const* d_in, const int* in_sizes, int n_in,
                              void* d_out, int out_size, void* d_ws, size_t ws_size,
                              hipStream_t stream) {
    const float* x  = (const float*)d_in[0];
    const float* k  = (const float*)d_in[1];
    const float* w1 = (const float*)d_in[2];
    const float* b1 = (const float*)d_in[3];
    const float* w2 = (const float*)d_in[4];
    float* out = (float*)d_out;

    const size_t slice = (size_t)in_sizes[0];           // 16*512*512 = 4194304
    const int steps = out_size / (int)slice - 1;        // 16
    const int B = (int)(slice / NCA_HW);                // 16

    const int blocks = B * 64;                          // 16 batches x 8x8 tiles
    for (int base = 0; base < steps; base += HALO) {
        int ns = steps - base;
        if (ns > HALO) ns = HALO;
        const float* s0 = (base == 0) ? x : (out + (size_t)base * slice);
        nca_fused<<<blocks, 256, 0, stream>>>(s0, out + (size_t)base * slice,
                                              slice, ns, (base == 0) ? 1 : 0,
                                              k, w1, b1, w2);
    }
}

// Round 6
// 448.650 us; speedup vs baseline: 1.0699x; 1.0110x over previous
//
#include <hip/hip_runtime.h>

// BasicNCA: x:(16,1,512,512) f32, k:(1,1,3,3), w1:(10,1), b1:(10), w2:(1,10), steps=16
// out: (steps+1, 16, 1, 512, 512) f32 trajectory.
//
// Temporal blocking, HALO=8 steps/kernel, 64x64 central tile.
// Round-6 == Round-5 resubmitted (container infra failure, no kernel signal).
// Structure (R4 was ~135us/kernel, ~80% wave-stall by the VALU model):
//  - SINGLE 80x80 LDS buffer, in-place step update in two phases:
//      phase A: rolling 4-row register window, results held in registers
//      phase B: ds_write results back + global trajectory stores
//    -> LDS 25.6 KB/block -> 4 blocks/CU fully resident (1024 blocks, no tail),
//       16 waves/CU, 4 independent barrier domains per SIMD.
//  - barriers are raw s_barrier + s_waitcnt lgkmcnt(0) ONLY (no vmcnt drain):
//    global stores to disjoint, never-re-read addresses stay in flight across
//    steps instead of serializing every step (__syncthreads drains vmcnt(0)).
//  - in-place safety: ALL LDS reads (phase A, into regs) precede ALL LDS writes
//    (phase B) within a step, separated by a barrier -> no cross-strip race.
//    Rows 0/79 stay stale (layer-0 cells: invalid by the layer invariant, finite).
// Wave-aligned strips (Round-4 fix kept): 60 active lanes/wave = 3 strips x 20
// column groups; shfl seam garbage only reaches cols 0/79 outputs (layer 0).
// Validity invariant: after step s, tile layer d valid iff d >= s; central 64x64 =
// layers >= 8. Out-of-image results pinned to exact 0 (SAME padding).
// Per-step math order identical to the 451us baseline (absmax 0.015625).

#define NCA_H 512
#define NCA_W 512
#define NCA_HW (NCA_H * NCA_W)
#define TX 80          // tile extent incl. halo
#define HALO 8         // steps fused per kernel launch
#define NG 20          // TX/4 column groups

// barrier with LDS-only wait (no vmcnt drain; stores float across steps)
#define BAR() do {                                             \
    asm volatile("s_waitcnt lgkmcnt(0)" ::: "memory");         \
    __builtin_amdgcn_s_barrier();                              \
    asm volatile("" ::: "memory");                             \
} while (0)

// load tile row 'rrow', cols w0-1..w0+4 into W[0..5] (edges via shfl)
#define LOADR(W, rrow) do {                                                  \
    const float4 q_ = *(const float4*)(buf + (rrow) * TX + w0);              \
    W[1] = q_.x; W[2] = q_.y; W[3] = q_.z; W[4] = q_.w;                      \
    W[0] = __shfl_up(q_.w, 1);                                               \
    W[5] = __shfl_down(q_.x, 1);                                             \
} while (0)

// compute row 'rrow' from window rows Wm/Wc/Wp into register float4 Rd (no stores)
#define COMPR(Wm, Wc, Wp, rrow, Rd) do {                                     \
    const int rr_ = (rrow);                                                  \
    const bool ok_ = colIn && ((unsigned)(gh0 + rr_) < NCA_H);               \
    float* rp_ = (float*)&(Rd);                                              \
    _Pragma("unroll")                                                        \
    for (int j = 0; j < 4; ++j) {                                            \
        float s_ = 0.f;                                                      \
        s_ = fmaf(kk[0], Wm[j],     s_);                                     \
        s_ = fmaf(kk[1], Wm[j + 1], s_);                                     \
        s_ = fmaf(kk[2], Wm[j + 2], s_);                                     \
        s_ = fmaf(kk[3], Wc[j],     s_);                                     \
        s_ = fmaf(kk[4], Wc[j + 1], s_);                                     \
        s_ = fmaf(kk[5], Wc[j + 2], s_);                                     \
        s_ = fmaf(kk[6], Wp[j],     s_);                                     \
        s_ = fmaf(kk[7], Wp[j + 1], s_);                                     \
        s_ = fmaf(kk[8], Wp[j + 2], s_);                                     \
        float d_ = s_ - 1.0f;                                                \
        float g_ = __expf(-d_ * d_);                                         \
        float a_ = 0.f;                                                      \
        _Pragma("unroll")                                                    \
        for (int o = 0; o < 10; ++o) {                                       \
            float h_ = fmaxf(fmaf(rw1[o], g_, rb1[o]), 0.f);                 \
            a_ = fmaf(rw2[o], h_, a_);                                       \
        }                                                                    \
        float sg_ = __fdividef(1.0f, 1.0f + __expf(-a_));                    \
        float v_ = Wc[j + 1] + (sg_ - 0.5f);                                 \
        rp_[j] = ok_ ? v_ : 0.f;                                             \
    }                                                                        \
} while (0)

// phase B: write row back to LDS in place + central-region global store
#define SROW(Rv, rrow) do {                                                  \
    const int rr_ = (rrow);                                                  \
    *(float4*)&buf[rr_ * TX + w0] = (Rv);                                    \
    if (colStore && rr_ >= HALO && rr_ < TX - HALO)                          \
        *(float4*)(gout + (size_t)(gh0 + rr_) * NCA_W + (gw0 + w0)) = (Rv);  \
} while (0)

__global__ __launch_bounds__(256, 4) void nca_fused(
        const float* __restrict__ src,   // state at step 'base' (x or traj slice)
        float* __restrict__ traj,        // points at slice 'base' of trajectory
        size_t slice, int nsteps, int writeInit,
        const float* __restrict__ kc, const float* __restrict__ w1v,
        const float* __restrict__ b1v, const float* __restrict__ w2v) {
    __shared__ float buf[TX * TX];   // 25.6 KB, single buffer (in-place)

    float kk[9];
#pragma unroll
    for (int i = 0; i < 9; ++i) kk[i] = kc[i];
    float rw1[10], rb1[10], rw2[10];
#pragma unroll
    for (int o = 0; o < 10; ++o) { rw1[o] = w1v[o]; rb1[o] = b1v[o]; rw2[o] = w2v[o]; }

    const int bi = blockIdx.x;
    const int b  = bi >> 6;            // batch
    const int ty = (bi >> 3) & 7;      // tile row
    const int tx = bi & 7;             // tile col
    const int gh0 = ty * 64 - HALO;
    const int gw0 = tx * 64 - HALO;

    // ---- stage 80x80 halo'd tile from src; kernel 1 also emits slice 0 ----
    const float* sp = src + (size_t)b * NCA_HW;
    float* ip = traj + (size_t)b * NCA_HW;
    for (int i = threadIdx.x; i < (TX * TX / 4); i += 256) {
        int row = i / NG;
        int c4  = i - row * NG;
        int gh  = gh0 + row;
        int gw  = gw0 + 4 * c4;
        float4 v = make_float4(0.f, 0.f, 0.f, 0.f);
        if (((unsigned)gh < NCA_H) && ((unsigned)gw < NCA_W))
            v = *(const float4*)(sp + (size_t)gh * NCA_W + gw);
        *(float4*)&buf[4 * i] = v;     // row*TX + 4*c4 == 4*i (20*16B == TX row)
        if (writeInit && row >= HALO && row < TX - HALO &&
            c4 >= (HALO / 4) && c4 < (TX - HALO) / 4)
            *(float4*)(ip + (size_t)gh * NCA_W + gw) = v;
    }
    BAR();

    // ---- wave-aligned mapping: 60 active lanes/wave = 3 strips x 20 groups;
    //      4 waves -> 12 strips covering rows 1..78 ----
    const int tid  = threadIdx.x;
    const int lane = tid & 63;
    const int wid  = tid >> 6;
    const bool active = lane < 60;
    const int g    = lane % 20;              // column group within strip
    const int sidx = wid * 3 + lane / 20;    // strip index 0..11
    const int w0   = g * 4;
    const int r0   = (sidx < 6) ? (1 + 7 * sidx) : (43 + 6 * (sidx - 6));
    const bool n7  = (sidx < 6);             // 7-row strip? (wave-uniform)
    const bool colStore = active && (w0 >= HALO) && (w0 < TX - HALO);
    const bool colIn = ((unsigned)(gw0 + w0) < NCA_W);

    for (int s = 1; s <= nsteps; ++s) {
        float* gout = traj + (size_t)s * slice + (size_t)b * NCA_HW;
        float4 R0, R1, R2, R3, R4, R5, R6;
        if (active) {
            float A[6], B[6], C[6], D[6];
            // phase A: all LDS reads + compute into registers (no LDS writes)
            LOADR(A, r0 - 1); LOADR(B, r0);
            LOADR(C, r0 + 1); LOADR(D, r0 + 2);
            COMPR(A, B, C, r0,     R0);  LOADR(A, r0 + 3);
            COMPR(B, C, D, r0 + 1, R1);  LOADR(B, r0 + 4);
            COMPR(C, D, A, r0 + 2, R2);  LOADR(C, r0 + 5);
            COMPR(D, A, B, r0 + 3, R3);  LOADR(D, r0 + 6);
            COMPR(A, B, C, r0 + 4, R4);
            COMPR(B, C, D, r0 + 5, R5);
            if (n7) { LOADR(A, r0 + 7); COMPR(C, D, A, r0 + 6, R6); }
        }
        BAR();   // all reads done -> safe to overwrite in place
        if (active) {
            SROW(R0, r0);     SROW(R1, r0 + 1);
            SROW(R2, r0 + 2); SROW(R3, r0 + 3);
            SROW(R4, r0 + 4); SROW(R5, r0 + 5);
            if (n7) SROW(R6, r0 + 6);
        }
        BAR();   // all writes visible before next step's reads
    }
}

extern "C" void kernel_launch(void* const* d_in, const int* in_sizes, int n_in,
                              void* d_out, int out_size, void* d_ws, size_t ws_size,
                              hipStream_t stream) {
    const float* x  = (const float*)d_in[0];
    const float* k  = (const float*)d_in[1];
    const float* w1 = (const float*)d_in[2];
    const float* b1 = (const float*)d_in[3];
    const float* w2 = (const float*)d_in[4];
    float* out = (float*)d_out;

    const size_t slice = (size_t)in_sizes[0];           // 16*512*512 = 4194304
    const int steps = out_size / (int)slice - 1;        // 16
    const int B = (int)(slice / NCA_HW);                // 16

    const int blocks = B * 64;                          // 16 batches x 8x8 tiles
    for (int base = 0; base < steps; base += HALO) {
        int ns = steps - base;
        if (ns > HALO) ns = HALO;
        const float* s0 = (base == 0) ? x : (out + (size_t)base * slice);
        nca_fused<<<blocks, 256, 0, stream>>>(s0, out + (size_t)base * slice,
                                              slice, ns, (base == 0) ? 1 : 0,
                                              k, w1, b1, w2);
    }
}